// Round 7
// baseline (253.672 us; speedup 1.0000x reference)
//
#include <hip/hip_runtime.h>
#include <hip/hip_bf16.h>

#define T_LEN 4096
#define DHEAD 64
#define WINSZ 128
#define NWIN 32
#define NBH 64
#define NWPB 4
#define NGRP (NWIN / NWPB)
#define FLTMAX 3.402823466e38f

typedef float f32x4 __attribute__((ext_vector_type(4)));
typedef short s16x8 __attribute__((ext_vector_type(8)));
typedef short s16x4 __attribute__((ext_vector_type(4)));

// float -> bf16 bits via native convert (RNE); compiler pairs into v_cvt_pk_bf16_f32
__device__ __forceinline__ unsigned short f2b(float x) {
  return __builtin_bit_cast(unsigned short, __float2bfloat16(x));
}

// RoPE table: tab[0 .. T*32) = cos, tab[T*32 .. 2*T*32) = sin
__global__ void rope_tab_kernel(float* __restrict__ tab) {
  const int idx = blockIdx.x * 256 + threadIdx.x;
  if (idx >= T_LEN * 32) return;
  const int t = idx >> 5;
  const int i = idx & 31;
  const float freq = powf(10000.0f, -(float)i / 32.0f);
  float s, c;
  sincosf((float)t * freq, &s, &c);
  tab[idx] = c;
  tab[T_LEN * 32 + idx] = s;
}

// One block per (batch-head, group of 4 consecutive windows). 512 threads = 8 waves.
// Ping-pong half-buffers: window t reads halves {buf[t&1]=prev, buf[(t+1)&1]=own};
// own(t) becomes prev(t+1); stage(t+1) overwrites buf[t&1] after a barrier.
// SWAPPED QK^T: mfma(A=K, B=Q) -> D: col(l15)=query, row(4g+r)=key.
// PV kappa(ks,g,j)=32ks+16*(j>>2)+4g+(j&3): A-frag = lane's own P values.
__global__ __launch_bounds__(512, 4) void lattn_kernel(
    const float* __restrict__ qg, const float* __restrict__ kg,
    const float* __restrict__ vg, const float* __restrict__ tab,
    float* __restrict__ outg) {
  // K half: [kr][d] ushort, idx = kr*64 + (d ^ ((kr&7)<<3))
  // V half: [d][kr] ushort, idx = d*128 + (kr ^ ((d&15)<<3))
  __shared__ __align__(16) unsigned short Kh[2][WINSZ * DHEAD];  // 16 KB x2
  __shared__ __align__(16) unsigned short Vh[2][DHEAD * WINSZ];  // 16 KB x2

  const int bid = blockIdx.x;
  const int grp = bid & (NGRP - 1);
  const int bh  = bid >> 3;
  const int tid = threadIdx.x;
  const int lane = tid & 63;
  const int wv = tid >> 6;          // 0..7
  const int l15 = lane & 15;
  const int g = lane >> 4;

  const size_t base = (size_t)bh * T_LEN * DHEAD;
  const int win0 = grp * NWPB;
  const bool use_tab = (tab != nullptr);
  const float* ct = tab;
  const float* st = tab + T_LEN * 32;

  // ---- stage one 128-key half: K (RoPE'd) + V(transposed), swizzled ----
  auto stage_half = [&](int hb, int kb) {
    {
      const int c = tid & 7;          // d-quad d0=4c (pairs at d0+32)
      const int rr = tid >> 3;        // 64 rows/pass
      #pragma unroll
      for (int p = 0; p < 2; ++p) {
        const int kr = p * 64 + rr;   // 0..127
        const int kt = kb + kr;
        float xa[4] = {0.f,0.f,0.f,0.f}, xb[4] = {0.f,0.f,0.f,0.f};
        float cs[4] = {1.f,1.f,1.f,1.f}, sn[4] = {0.f,0.f,0.f,0.f};
        if (kt >= 0) {
          const float* kp = kg + base + (size_t)kt * DHEAD + 4 * c;
          *(float4*)xa = *(const float4*)kp;
          *(float4*)xb = *(const float4*)(kp + 32);
          if (use_tab) {
            *(float4*)cs = *(const float4*)(ct + kt * 32 + 4 * c);
            *(float4*)sn = *(const float4*)(st + kt * 32 + 4 * c);
          } else {
            #pragma unroll
            for (int j = 0; j < 4; ++j) {
              const float f = powf(10000.0f, -(float)(4 * c + j) / 32.0f);
              sincosf((float)kt * f, &sn[j], &cs[j]);
            }
          }
        }
        unsigned wlo[2], whi[2];
        #pragma unroll
        for (int h = 0; h < 2; ++h) {
          const int j0 = 2 * h, j1 = 2 * h + 1;
          wlo[h] = (unsigned)f2b(xa[j0]*cs[j0] - xb[j0]*sn[j0]) |
                   ((unsigned)f2b(xa[j1]*cs[j1] - xb[j1]*sn[j1]) << 16);
          whi[h] = (unsigned)f2b(xb[j0]*cs[j0] + xa[j0]*sn[j0]) |
                   ((unsigned)f2b(xb[j1]*cs[j1] + xa[j1]*sn[j1]) << 16);
        }
        const int su = (kr & 7) << 3;
        *(uint2*)&Kh[hb][kr * 64 + ((4 * c) ^ su)] = uint2{wlo[0], wlo[1]};
        *(uint2*)&Kh[hb][kr * 64 + ((4 * c + 32) ^ su)] = uint2{whi[0], whi[1]};
      }
    }
    {
      const int c = tid & 15;         // d0 = 4c
      const int rp = tid >> 4;        // 32 row-pairs/pass
      #pragma unroll
      for (int p = 0; p < 2; ++p) {
        const int kr = (p * 32 + rp) * 2;   // even
        const int kt = kb + kr;
        float va[4] = {0.f,0.f,0.f,0.f}, vb[4] = {0.f,0.f,0.f,0.f};
        if (kt >= 0)
          *(float4*)va = *(const float4*)(vg + base + (size_t)kt * DHEAD + 4 * c);
        if (kt + 1 >= 0)
          *(float4*)vb = *(const float4*)(vg + base + (size_t)(kt + 1) * DHEAD + 4 * c);
        #pragma unroll
        for (int j = 0; j < 4; ++j) {
          const int d = 4 * c + j;
          const unsigned val = (unsigned)f2b(va[j]) | ((unsigned)f2b(vb[j]) << 16);
          *(unsigned*)&Vh[hb][d * WINSZ + (kr ^ ((d & 15) << 3))] = val;
        }
      }
    }
  };

  stage_half(0, win0 * WINSZ - WINSZ);   // prev half (zeros/pad if grp==0)
  stage_half(1, win0 * WINSZ);           // own half of first window

  #pragma unroll 1
  for (int t = 0; t < NWPB; ++t) {
    const int win = win0 + t;
    const int q0 = win * WINSZ;
    const int pb = t & 1, ob = (t + 1) & 1;

    // ---- Q: global -> RoPE -> B-fragments (no LDS; overlaps staging drain) --
    s16x8 qa0, qa1;
    {
      const int qrow = q0 + wv * 16 + l15;
      const float* qp = qg + base + (size_t)qrow * DHEAD + 8 * g;
      float xa[8], xb[8], cs[8], sn[8];
      *(float4*)&xa[0] = *(const float4*)qp;
      *(float4*)&xa[4] = *(const float4*)(qp + 4);
      *(float4*)&xb[0] = *(const float4*)(qp + 32);
      *(float4*)&xb[4] = *(const float4*)(qp + 36);
      if (use_tab) {
        const float* cp = ct + qrow * 32 + 8 * g;
        const float* sp = st + qrow * 32 + 8 * g;
        *(float4*)&cs[0] = *(const float4*)cp;
        *(float4*)&cs[4] = *(const float4*)(cp + 4);
        *(float4*)&sn[0] = *(const float4*)sp;
        *(float4*)&sn[4] = *(const float4*)(sp + 4);
      } else {
        #pragma unroll
        for (int j = 0; j < 8; ++j) {
          const float f = powf(10000.0f, -(float)(8 * g + j) / 32.0f);
          sincosf((float)qrow * f, &sn[j], &cs[j]);
        }
      }
      #pragma unroll
      for (int j = 0; j < 8; ++j) {
        qa0[j] = (short)f2b(xa[j]*cs[j] - xb[j]*sn[j]);
        qa1[j] = (short)f2b(xb[j]*cs[j] + xa[j]*sn[j]);
      }
    }

    __syncthreads();   // staged halves visible

    // ---- QK^T (swapped) + mask + softmax -> unnormalized P frags ------------
    s16x8 pa[8];
    float inv;
    {
      f32x4 acc[16];
      #pragma unroll
      for (int nt = 0; nt < 16; ++nt) acc[nt] = f32x4{0.f, 0.f, 0.f, 0.f};
      #pragma unroll
      for (int nt = 0; nt < 16; ++nt) {
        const int hb = (nt < 8) ? pb : ob;
        const int krh = (nt & 7) * 16 + l15;
        const int su = (krh & 7) << 3;
        const s16x8 k0f = *(const s16x8*)&Kh[hb][krh * 64 + ((8 * g) ^ su)];
        const s16x8 k1f = *(const s16x8*)&Kh[hb][krh * 64 + ((8 * g + 32) ^ su)];
        acc[nt] = __builtin_amdgcn_mfma_f32_16x16x32_bf16(k0f, qa0, acc[nt], 0, 0, 0);
        acc[nt] = __builtin_amdgcn_mfma_f32_16x16x32_bf16(k1f, qa1, acc[nt], 0, 0, 0);
      }
      const int qloc = wv * 16 + l15;
      float mx = -FLTMAX;
      #pragma unroll
      for (int nt = 0; nt < 16; ++nt) {
        const bool pad = (win == 0) && (nt < 8);
        #pragma unroll
        for (int r = 0; r < 4; ++r) {
          const int kloc = nt * 16 + 4 * g + r;
          const bool msk = pad || (kloc > WINSZ + qloc);
          const float s = msk ? -FLTMAX : acc[nt][r];
          acc[nt][r] = s;
          mx = fmaxf(mx, s);
        }
      }
      mx = fmaxf(mx, __shfl_xor(mx, 16));
      mx = fmaxf(mx, __shfl_xor(mx, 32));
      float den = 0.f;
      #pragma unroll
      for (int nt = 0; nt < 16; ++nt) {
        #pragma unroll
        for (int r = 0; r < 4; ++r) {
          const float pv = __expf(0.125f * (acc[nt][r] - mx));  // scale e^-0.5
          acc[nt][r] = pv;
          den += pv;
        }
      }
      den += __shfl_xor(den, 16);
      den += __shfl_xor(den, 32);
      inv = 1.0f / den;
      #pragma unroll
      for (int ks = 0; ks < 8; ++ks) {
        #pragma unroll
        for (int j = 0; j < 4; ++j) {
          pa[ks][j]     = (short)f2b(acc[2 * ks][j]);
          pa[ks][j + 4] = (short)f2b(acc[2 * ks + 1][j]);
        }
      }
    }

    // ---- O = P @ V (kappa mapping; halves pb then ob) -----------------------
    f32x4 oacc[4];
    #pragma unroll
    for (int nt = 0; nt < 4; ++nt) oacc[nt] = f32x4{0.f, 0.f, 0.f, 0.f};
    #pragma unroll
    for (int ks = 0; ks < 8; ++ks) {
      const int hb = (ks < 4) ? pb : ob;
      const int c1 = (ks & 3) * 32 + 4 * g;
      #pragma unroll
      for (int nt = 0; nt < 4; ++nt) {
        const int d = nt * 16 + l15;
        const int su = (d & 15) << 3;
        const s16x4 v0 = *(const s16x4*)&Vh[hb][d * WINSZ + (c1 ^ su)];
        const s16x4 v1 = *(const s16x4*)&Vh[hb][d * WINSZ + ((c1 + 16) ^ su)];
        const s16x8 vb = __builtin_shufflevector(v0, v1, 0, 1, 2, 3, 4, 5, 6, 7);
        oacc[nt] = __builtin_amdgcn_mfma_f32_16x16x32_bf16(pa[ks], vb, oacc[nt], 0, 0, 0);
      }
    }

    // ---- epilogue: normalize via shfl'd 1/den, store ------------------------
    float* op = outg + base;
    #pragma unroll
    for (int r = 0; r < 4; ++r) {
      const float ir = __shfl(inv, 4 * g + r, 64);
      const int qrow = q0 + wv * 16 + 4 * g + r;
      #pragma unroll
      for (int nt = 0; nt < 4; ++nt)
        op[(size_t)qrow * DHEAD + nt * 16 + l15] = oacc[nt][r] * ir;
    }

    if (t + 1 < NWPB) {
      __syncthreads();                       // all reads of buf[t&1] done
      stage_half(t & 1, (win + 1) * WINSZ);  // next own-half overwrites old prev
    }
  }
}

extern "C" void kernel_launch(void* const* d_in, const int* in_sizes, int n_in,
                              void* d_out, int out_size, void* d_ws, size_t ws_size,
                              hipStream_t stream) {
  (void)in_sizes; (void)n_in; (void)out_size;
  const float* q = (const float*)d_in[0];
  const float* k = (const float*)d_in[1];
  const float* v = (const float*)d_in[2];
  float* out = (float*)d_out;

  float* tab = nullptr;
  const size_t tab_bytes = (size_t)2 * T_LEN * 32 * sizeof(float);  // 1 MB
  if (ws_size >= tab_bytes) {
    tab = (float*)d_ws;
    rope_tab_kernel<<<dim3((T_LEN * 32 + 255) / 256), dim3(256), 0, stream>>>(tab);
  }
  lattn_kernel<<<dim3(NBH * NGRP), dim3(512), 0, stream>>>(q, k, v, tab, out);
}